// Round 2
// baseline (140.866 us; speedup 1.0000x reference)
//
#include <hip/hip_runtime.h>
#include <hip/hip_bf16.h>
#include <stdint.h>
#include <stddef.h>

#define L_LEN 4096
#define CIN   128
#define COUT  128
#define NB    32
#define KTOT  384            // 3 * CIN, kappa = k*128 + i
#define TN    64             // h-tile per pipeline stage
#define TPB   4              // tiles per block (pipelined)
#define ROWS  (TN + 2)       // 66 (halo of 1 on each side)

typedef __bf16 bf16x8 __attribute__((ext_vector_type(8)));
typedef float  f32x4  __attribute__((ext_vector_type(4)));

__device__ __forceinline__ uint16_t f2bf(float f) {
    union { float f; uint32_t u; } v; v.f = f;
    return (uint16_t)((v.u + 0x7fffu + ((v.u >> 16) & 1u)) >> 16);  // RNE
}
__device__ __forceinline__ uint32_t pack2(float lo, float hi) {
    return (uint32_t)f2bf(lo) | ((uint32_t)f2bf(hi) << 16);
}

// ---- Prologue: combined bf16 weights in MFMA-FRAGMENT order + cbias ----
// Wc index = (((b*4 + og)*12 + t)*2 + mt)*512 + lane*8 + j
//   o   = og*32 + mt*16 + (lane&15)
//   col = t*32 + (lane>>4)*8 + j        (col = k*128 + i)
__global__ __launch_bounds__(256) void geps_combine(
    const float* __restrict__ codes, const float* __restrict__ weight,
    const float* __restrict__ Amat,  const float* __restrict__ Bmat,
    const float* __restrict__ bias,  const float* __restrict__ bias_ctx,
    uint16_t* __restrict__ Wc, float* __restrict__ cbias)
{
    int tid = blockIdx.x * 256 + threadIdx.x;
    if (tid < NB * COUT * KTOT) {
        int j    = tid & 7;
        int lane = (tid >> 3) & 63;
        int mt   = (tid >> 9) & 1;
        int tmp  = tid >> 10;
        int t    = tmp % 12;
        int bo   = tmp / 12;          // b*4 + og
        int og   = bo & 3;
        int b    = bo >> 2;
        int col  = t * 32 + (lane >> 4) * 8 + j;   // kappa = k*128 + i
        int k    = col >> 7;
        int i    = col & 127;
        int o    = og * 32 + mt * 16 + (lane & 15);
        float cw = 0.f;
        #pragma unroll
        for (int c = 0; c < 2; ++c) {
            float a = Amat[i * 6 + c * 3 + k];
            #pragma unroll
            for (int r = 0; r < 2; ++r)
                cw += a * codes[b * 4 + c * 2 + r] * Bmat[o * 6 + r * 3 + k];
        }
        float val = weight[o * 384 + i * 3 + k] + cw;   // FACTOR = 1
        Wc[tid] = f2bf(val);
    }
    if (tid < NB * COUT) {
        int b = tid >> 7, o = tid & 127;
        float cb = bias[o];
        #pragma unroll
        for (int c = 0; c < 2; ++c)
            cb += codes[b * 4 + c * 2 + c] * bias_ctx[c * 128 + o];
        cbias[tid] = cb;
    }
}

// Stage a tile's input into registers (issue only; no wait).
#define LOAD_TILE(H0)                                                        \
    {                                                                        \
        const float* tb = inb + (H0);                                        \
        _Pragma("unroll")                                                    \
        for (int it = 0; it < 2; ++it) {                                     \
            int task = it * 256 + tid;                                       \
            int p4   = task >> 4;                                            \
            int qd   = task & 15;                                            \
            const float* r0 = tb + (size_t)(4 * p4) * L_LEN + 4 * qd;        \
            st[it][0] = *(const float4*)(r0);                                \
            st[it][1] = *(const float4*)(r0 + L_LEN);                        \
            st[it][2] = *(const float4*)(r0 + 2 * L_LEN);                    \
            st[it][3] = *(const float4*)(r0 + 3 * L_LEN);                    \
        }                                                                    \
        if (tid < 128) {                                                     \
            int p    = tid & 63;                                             \
            int side = tid >> 6;                                             \
            int r    = side ? (ROWS - 1) : 0;                                \
            int gh   = ((H0) - 1 + r) & (L_LEN - 1);                         \
            hx0 = inb[(size_t)(2 * p) * L_LEN + gh];                         \
            hx1 = inb[(size_t)(2 * p + 1) * L_LEN + gh];                     \
        }                                                                    \
    }

// Convert staged registers to bf16 and write the swizzled LDS tile.
// (compiler inserts the vmcnt wait before first use of st/hx)
#define PACK_TILE(XP)                                                        \
    {                                                                        \
        uint16_t* Xw = (XP);                                                 \
        _Pragma("unroll")                                                    \
        for (int it = 0; it < 2; ++it) {                                     \
            int task = it * 256 + tid;                                       \
            int p4   = task >> 4;                                            \
            int qd   = task & 15;                                            \
            const int off = (4 * p4) & 7;                                    \
            const int pc  = p4 >> 1;                                         \
            _Pragma("unroll")                                                \
            for (int j4 = 0; j4 < 4; ++j4) {                                 \
                int r  = 1 + 4 * qd + j4;                                    \
                int ch = pc ^ (r & 15);                                      \
                uint2 w;                                                     \
                w.x = pack2(((const float*)&st[it][0])[j4],                  \
                            ((const float*)&st[it][1])[j4]);                 \
                w.y = pack2(((const float*)&st[it][2])[j4],                  \
                            ((const float*)&st[it][3])[j4]);                 \
                *(uint2*)&Xw[r * 128 + (ch << 3) + off] = w;                 \
            }                                                                \
        }                                                                    \
        if (tid < 128) {                                                     \
            int p     = tid & 63;                                            \
            int side  = tid >> 6;                                            \
            int r     = side ? (ROWS - 1) : 0;                               \
            int chunk = (p >> 2) ^ (r & 15);                                 \
            *(uint32_t*)&Xw[r * 128 + (chunk << 3) + ((2 * p) & 7)] =        \
                pack2(hx0, hx1);                                             \
        }                                                                    \
    }

// ---- Main: per-batch GEMM, M=o(128) x N=h x K=384, bf16 MFMA ----
// Each block pipelines TPB=4 consecutive h-tiles with double-buffered Xt:
// global loads of tile j+1 and stores of tile j drain under tile j's
// MFMA/LDS phase, keeping HBM busy regardless of inter-block scheduling.
// af[12][2] (the wave's whole A panel, 96 VGPRs) is tile-invariant and
// preloaded once. Grid = 512 blocks = exactly 2 blocks/CU (256-reg budget).
__global__ __launch_bounds__(256, 2) void geps_conv(
    const float* __restrict__ in, const uint16_t* __restrict__ Wc,
    const float* __restrict__ cbias, float* __restrict__ out)
{
    // Xt: element (r,i) at r*128 + (((i>>3)^(r&15))<<3) + (i&7)
    __shared__ uint16_t __attribute__((aligned(16))) Xt[2][ROWS * 128];
    __shared__ float cb[COUT];

    const int tid  = threadIdx.x;
    const int b    = blockIdx.y;
    const int hb   = blockIdx.x * (TN * TPB);
    const int lane = tid & 63;
    const int wid  = tid >> 6;
    const int m16  = lane & 15;
    const int q    = lane >> 4;
    const int mq   = wid * 32;           // wave's o-offset (4 waves x 32 o)

    if (tid < COUT) cb[tid] = cbias[b * COUT + tid];

    const float* inb = in + (size_t)b * CIN * L_LEN;

    // --- A panel preload: 12 steps x 2 mt, fragment-ordered, 1KiB/wave/load
    const uint16_t* WcW = Wc + (size_t)(b * 4 + wid) * 12288 + lane * 8;
    bf16x8 af[12][2];
    #pragma unroll
    for (int t = 0; t < 12; ++t) {
        af[t][0] = *(const bf16x8*)(WcW + t * 1024);
        af[t][1] = *(const bf16x8*)(WcW + t * 1024 + 512);
    }

    float4 st[2][4];
    float  hx0 = 0.f, hx1 = 0.f;

    // --- prologue: stage tile 0 (latency exposed once per block)
    LOAD_TILE(hb)
    PACK_TILE(&Xt[0][0])
    __syncthreads();

    f32x4 acc[2][4];

    #pragma unroll 1
    for (int j = 0; j < TPB; ++j) {
        const int h0 = hb + j * TN;
        const uint16_t* X = &Xt[j & 1][0];

        // issue next tile's loads NOW; they land during the K-loop below
        if (j + 1 < TPB) LOAD_TILE(h0 + TN)
        asm volatile("" ::: "memory");   // pin load-issue above the K-loop

        #pragma unroll
        for (int a = 0; a < 2; ++a)
            #pragma unroll
            for (int c = 0; c < 4; ++c) acc[a][c] = 0.0f;

        #pragma unroll
        for (int t = 0; t < 12; ++t) {
            const int k   = t >> 2;          // kernel tap of this K-step
            const int i0c = (t & 3) << 2;    // i-chunk base
            bf16x8 bfv[4];
            #pragma unroll
            for (int nt = 0; nt < 4; ++nt) {
                int r  = nt * 16 + m16 + k;  // Xt row = h_local + k
                int ch = (i0c + q) ^ (r & 15);
                bfv[nt] = *(const bf16x8*)&X[r * 128 + (ch << 3)];
            }
            #pragma unroll
            for (int nt = 0; nt < 4; ++nt) {
                acc[0][nt] = __builtin_amdgcn_mfma_f32_16x16x32_bf16(
                    af[t][0], bfv[nt], acc[0][nt], 0, 0, 0);
                acc[1][nt] = __builtin_amdgcn_mfma_f32_16x16x32_bf16(
                    af[t][1], bfv[nt], acc[1][nt], 0, 0, 0);
            }
        }

        // --- epilogue: C/D layout col=lane&15 (h), row=(lane>>4)*4+reg (o)
        float* outb = out + (size_t)b * COUT * L_LEN + h0;
        #pragma unroll
        for (int mt = 0; mt < 2; ++mt) {
            #pragma unroll
            for (int reg = 0; reg < 4; ++reg) {
                int o = mq + mt * 16 + q * 4 + reg;
                float bv = cb[o];
                float* orow = outb + (size_t)o * L_LEN;
                #pragma unroll
                for (int nt = 0; nt < 4; ++nt)
                    __builtin_nontemporal_store(acc[mt][nt][reg] + bv,
                                                &orow[nt * 16 + m16]);
            }
        }

        // pack next tile into the other buffer; stores drain meanwhile
        if (j + 1 < TPB) {
            PACK_TILE(&Xt[(j + 1) & 1][0])
            __syncthreads();
        }
    }
}

extern "C" void kernel_launch(void* const* d_in, const int* in_sizes, int n_in,
                              void* d_out, int out_size, void* d_ws, size_t ws_size,
                              hipStream_t stream) {
    const float* input    = (const float*)d_in[0];
    const float* codes    = (const float*)d_in[1];
    const float* weight   = (const float*)d_in[2];
    const float* Amat     = (const float*)d_in[3];
    const float* Bmat     = (const float*)d_in[4];
    const float* bias     = (const float*)d_in[5];
    const float* bias_ctx = (const float*)d_in[6];
    float* out = (float*)d_out;

    uint16_t* Wc    = (uint16_t*)d_ws;
    float*    cbias = (float*)((char*)d_ws + (size_t)NB * COUT * KTOT * 2);

    geps_combine<<<dim3((NB * COUT * KTOT) / 256), 256, 0, stream>>>(
        codes, weight, Amat, Bmat, bias, bias_ctx, Wc, cbias);
    geps_conv<<<dim3(L_LEN / (TN * TPB), NB), 256, 0, stream>>>(
        input, Wc, cbias, out);
}